// Round 4
// baseline (113.207 us; speedup 1.0000x reference)
//
#include <hip/hip_runtime.h>
#include <math.h>

// Problem constants (from reference):
// x: (32, 256, 112, 112) fp32, W: (1, 2, 7, 7) fp32, out: (32, 1, 112, 112) fp32
#define BATCH 32
#define CH    256
#define HH    112
#define WW    112
#define HW    (HH * WW)     // 12544
#define HW4   (HW / 4)      // 3136 = 7 * 448

// ---- fully-sequential pool (channel-group partials) ------------------------
#define NG    8             // channel groups
#define CPG   (CH / NG)     // 32 channels per group
#define PT    448           // threads per pool block (7 waves)
#define KK    (HW4 / PT)    // 7 float4 slots per thread

// Each block owns (batch b, channel group g): reads CPG consecutive channel
// planes = 1.6 MB FULLY SEQUENTIAL (max DRAM row locality). Accumulators in
// registers (static indexing). Partial sum/max planes written to workspace.
__global__ __launch_bounds__(PT) void sa_pool_part_kernel(
    const float4* __restrict__ x4,
    float4* __restrict__ sum_part,   // [NG][BATCH][HW4]
    float4* __restrict__ max_part)   // [NG][BATCH][HW4]
{
    int tid = threadIdx.x;
    int b   = blockIdx.x;
    int g   = blockIdx.y;

    const float4* p = x4 + ((size_t)b * CH + (size_t)g * CPG) * HW4;

    float4 s[KK], m[KK];
    #pragma unroll
    for (int k = 0; k < KK; ++k) {
        s[k] = make_float4(0.f, 0.f, 0.f, 0.f);
        m[k] = make_float4(-INFINITY, -INFINITY, -INFINITY, -INFINITY);
    }

    #pragma unroll 2
    for (int c = 0; c < CPG; ++c) {
        const float4* pc = p + (size_t)c * HW4 + tid;
        #pragma unroll
        for (int k = 0; k < KK; ++k) {
            float4 v = pc[k * PT];
            s[k].x += v.x; s[k].y += v.y; s[k].z += v.z; s[k].w += v.w;
            m[k].x = fmaxf(m[k].x, v.x);
            m[k].y = fmaxf(m[k].y, v.y);
            m[k].z = fmaxf(m[k].z, v.z);
            m[k].w = fmaxf(m[k].w, v.w);
        }
    }

    float4* so = sum_part + ((size_t)g * BATCH + b) * HW4 + tid;
    float4* mo = max_part + ((size_t)g * BATCH + b) * HW4 + tid;
    #pragma unroll
    for (int k = 0; k < KK; ++k) {
        so[k * PT] = s[k];
        mo[k * PT] = m[k];
    }
}

// ---- conv + on-the-fly partial combine -------------------------------------
#define TILE 16
#define TW   (TILE + 6)     // 22

__global__ __launch_bounds__(256) void sa_conv_comb_kernel(
    const float* __restrict__ sum_part,  // [NG][BATCH][HW]
    const float* __restrict__ max_part,
    const float* __restrict__ wt,        // [2][7][7]
    float* __restrict__ out)
{
    __shared__ float t0[TW][TW];
    __shared__ float t1[TW][TW];
    __shared__ float w[2][49];

    int tid = threadIdx.x;
    int b   = blockIdx.z;
    int ty0 = blockIdx.y * TILE;
    int tx0 = blockIdx.x * TILE;

    if (tid < 98) w[tid / 49][tid % 49] = wt[tid];

    const float inv = 1.0f / (float)CH;

    for (int idx = tid; idx < TW * TW; idx += 256) {
        int iy = idx / TW;
        int ix = idx - iy * TW;
        int gy = ty0 + iy - 3;
        int gx = tx0 + ix - 3;
        bool ok = (gy >= 0) && (gy < HH) && (gx >= 0) && (gx < WW);
        float ssum = 0.f, mmax = -INFINITY;
        if (ok) {
            size_t gofs = (size_t)b * HW + gy * WW + gx;
            #pragma unroll
            for (int g = 0; g < NG; ++g) {
                ssum += sum_part[(size_t)g * (BATCH * HW) + gofs];
                mmax = fmaxf(mmax, max_part[(size_t)g * (BATCH * HW) + gofs]);
            }
        }
        t0[iy][ix] = ok ? ssum * inv : 0.f;   // zero-padding for conv
        t1[iy][ix] = ok ? mmax : 0.f;
    }
    __syncthreads();

    int oy = tid >> 4;
    int ox = tid & 15;

    float acc = 0.0f;
    #pragma unroll
    for (int i = 0; i < 7; ++i) {
        #pragma unroll
        for (int j = 0; j < 7; ++j) {
            acc += w[0][i * 7 + j] * t0[oy + i][ox + j];
            acc += w[1][i * 7 + j] * t1[oy + i][ox + j];
        }
    }

    float y = 1.0f / (1.0f + expf(-acc));
    out[b * HW + (ty0 + oy) * WW + (tx0 + ox)] = y;
}

// ---- fallback path (r3): used only if ws_size is too small -----------------
#define CHUNK 448

__global__ __launch_bounds__(448) void sa_pool_kernel_fb(
    const float4* __restrict__ x4,
    float4* __restrict__ avg4,
    float4* __restrict__ max4)
{
    int tid = threadIdx.x;
    int b   = blockIdx.y;
    int q   = blockIdx.x * CHUNK + tid;

    const float4* p = x4 + (size_t)b * (CH * HW4) + q;

    float4 s = make_float4(0.f, 0.f, 0.f, 0.f);
    float4 m = make_float4(-INFINITY, -INFINITY, -INFINITY, -INFINITY);

    #pragma unroll 8
    for (int c = 0; c < CH; ++c) {
        float4 v = p[(size_t)c * HW4];
        s.x += v.x; s.y += v.y; s.z += v.z; s.w += v.w;
        m.x = fmaxf(m.x, v.x);
        m.y = fmaxf(m.y, v.y);
        m.z = fmaxf(m.z, v.z);
        m.w = fmaxf(m.w, v.w);
    }

    const float inv = 1.0f / (float)CH;
    float4 a = make_float4(s.x * inv, s.y * inv, s.z * inv, s.w * inv);

    int g = b * HW4 + q;
    avg4[g] = a;
    max4[g] = m;
}

__global__ __launch_bounds__(256) void sa_conv_kernel_fb(
    const float* __restrict__ avgp,
    const float* __restrict__ maxp,
    const float* __restrict__ wt,
    float* __restrict__ out)
{
    __shared__ float t0[TW][TW];
    __shared__ float t1[TW][TW];
    __shared__ float w[2][49];

    int tid = threadIdx.x;
    int b   = blockIdx.z;
    int ty0 = blockIdx.y * TILE;
    int tx0 = blockIdx.x * TILE;

    if (tid < 98) w[tid / 49][tid % 49] = wt[tid];

    const float* ap = avgp + b * HW;
    const float* mp = maxp + b * HW;

    for (int idx = tid; idx < TW * TW; idx += 256) {
        int iy = idx / TW;
        int ix = idx - iy * TW;
        int gy = ty0 + iy - 3;
        int gx = tx0 + ix - 3;
        bool ok = (gy >= 0) && (gy < HH) && (gx >= 0) && (gx < WW);
        int gofs = gy * WW + gx;
        t0[iy][ix] = ok ? ap[gofs] : 0.0f;
        t1[iy][ix] = ok ? mp[gofs] : 0.0f;
    }
    __syncthreads();

    int oy = tid >> 4;
    int ox = tid & 15;

    float acc = 0.0f;
    #pragma unroll
    for (int i = 0; i < 7; ++i) {
        #pragma unroll
        for (int j = 0; j < 7; ++j) {
            acc += w[0][i * 7 + j] * t0[oy + i][ox + j];
            acc += w[1][i * 7 + j] * t1[oy + i][ox + j];
        }
    }

    float y = 1.0f / (1.0f + expf(-acc));
    out[b * HW + (ty0 + oy) * WW + (tx0 + ox)] = y;
}

// ---------------------------------------------------------------------------
extern "C" void kernel_launch(void* const* d_in, const int* in_sizes, int n_in,
                              void* d_out, int out_size, void* d_ws, size_t ws_size,
                              hipStream_t stream)
{
    const float* x  = (const float*)d_in[0];
    const float* wt = (const float*)d_in[1];
    float* out = (float*)d_out;

    const size_t plane_elems = (size_t)BATCH * HW;
    const size_t need = (size_t)NG * plane_elems * sizeof(float) * 2;

    if (ws_size >= need) {
        // main path: fully-sequential streams + fused combine
        float* sum_part = (float*)d_ws;
        float* max_part = sum_part + (size_t)NG * plane_elems;

        dim3 grid1(BATCH, NG);   // 256 blocks, 1/CU
        sa_pool_part_kernel<<<grid1, PT, 0, stream>>>(
            (const float4*)x, (float4*)sum_part, (float4*)max_part);

        dim3 grid2(WW / TILE, HH / TILE, BATCH);
        sa_conv_comb_kernel<<<grid2, 256, 0, stream>>>(sum_part, max_part, wt, out);
    } else {
        // fallback (r3 path): needs only 3.2 MB
        float* avgp = (float*)d_ws;
        float* maxp = avgp + plane_elems;

        dim3 grid1(HW4 / CHUNK, BATCH);
        sa_pool_kernel_fb<<<grid1, CHUNK, 0, stream>>>(
            (const float4*)x, (float4*)avgp, (float4*)maxp);

        dim3 grid2(WW / TILE, HH / TILE, BATCH);
        sa_conv_kernel_fb<<<grid2, 256, 0, stream>>>(avgp, maxp, wt, out);
    }
}

// Round 6
// 76.721 us; speedup vs baseline: 1.4756x; 1.4756x over previous
//
#include <hip/hip_runtime.h>
#include <math.h>

// Problem constants (from reference):
// x: (32, 256, 112, 112) fp32, W: (1, 2, 7, 7) fp32, out: (32, 1, 112, 112) fp32
#define BATCH 32
#define CH    256
#define HH    112
#define WW    112
#define HW    (HH * WW)     // 12544
#define HW4   (HW / 4)      // 3136 = 7 * 448

#define CHUNK 448           // float4s per block (7 waves x 64 lanes)

// native clang vector type — accepted by __builtin_nontemporal_load
typedef float f32x4 __attribute__((ext_vector_type(4)));

// ---------------------------------------------------------------------------
// Kernel 1: channel-wise mean + max reduction (r3 structure, best so far).
// Block = 448 threads (7 waves), each thread owns one float4 spatial position.
// Per channel step the block reads 448 x 16B = 7 KiB contiguous.
// NEW vs r3:
//  - per-block channel-start stagger: decorrelates the HBM channel-interleave
//    phase across the 224 concurrent blocks (they otherwise walk channels in
//    lockstep at congruent addresses -> transient memory-channel hotspots).
//  - nontemporal loads for the 411 MB x stream (read-once; don't thrash L3).
// ---------------------------------------------------------------------------
__global__ __launch_bounds__(448) void sa_pool_kernel(
    const f32x4* __restrict__ x4,
    f32x4* __restrict__ avg4,
    f32x4* __restrict__ max4)
{
    int tid = threadIdx.x;
    int b   = blockIdx.y;
    int q   = blockIdx.x * CHUNK + tid;   // float4 index within the HxW plane

    const f32x4* p = x4 + (size_t)b * (CH * HW4) + q;

    // stagger channel start per block to spread DRAM channel phase
    int c0 = (blockIdx.x * 37 + blockIdx.y * 11) & (CH - 1);

    f32x4 s = (f32x4){0.f, 0.f, 0.f, 0.f};
    f32x4 m = (f32x4){-INFINITY, -INFINITY, -INFINITY, -INFINITY};

    #pragma unroll 8
    for (int cc = 0; cc < CH; ++cc) {
        int c = cc + c0;
        c -= (c >= CH) ? CH : 0;
        f32x4 v = __builtin_nontemporal_load(p + (size_t)c * HW4);
        s.x += v.x; s.y += v.y; s.z += v.z; s.w += v.w;
        m.x = fmaxf(m.x, v.x);
        m.y = fmaxf(m.y, v.y);
        m.z = fmaxf(m.z, v.z);
        m.w = fmaxf(m.w, v.w);
    }

    const float inv = 1.0f / (float)CH;
    f32x4 a;
    a.x = s.x * inv; a.y = s.y * inv; a.z = s.z * inv; a.w = s.w * inv;

    int g = b * HW4 + q;
    avg4[g] = a;
    max4[g] = m;
}

// ---------------------------------------------------------------------------
// Kernel 2: 7x7 conv (2 in-ch -> 1 out-ch, pad 3) + sigmoid (unchanged r3).
// 16x16 output tile / block; halo tile 22x22 per channel in LDS; weights in
// LDS. 112/16 = 7 exactly -> no output bounds checks.
// ---------------------------------------------------------------------------
#define TILE 16
#define TW   (TILE + 6)     // 22

__global__ __launch_bounds__(256) void sa_conv_kernel(
    const float* __restrict__ avgp,
    const float* __restrict__ maxp,
    const float* __restrict__ wt,    // [2][7][7] flat (O=1, OIHW)
    float* __restrict__ out)
{
    __shared__ float t0[TW][TW];
    __shared__ float t1[TW][TW];
    __shared__ float w[2][49];

    int tid = threadIdx.x;
    int b   = blockIdx.z;
    int ty0 = blockIdx.y * TILE;
    int tx0 = blockIdx.x * TILE;

    if (tid < 98) w[tid / 49][tid % 49] = wt[tid];

    const float* ap = avgp + b * HW;
    const float* mp = maxp + b * HW;

    for (int idx = tid; idx < TW * TW; idx += 256) {
        int iy = idx / TW;
        int ix = idx - iy * TW;
        int gy = ty0 + iy - 3;
        int gx = tx0 + ix - 3;
        bool ok = (gy >= 0) && (gy < HH) && (gx >= 0) && (gx < WW);
        int gofs = gy * WW + gx;
        t0[iy][ix] = ok ? ap[gofs] : 0.0f;
        t1[iy][ix] = ok ? mp[gofs] : 0.0f;
    }
    __syncthreads();

    int oy = tid >> 4;          // 0..15
    int ox = tid & 15;          // 0..15

    float acc = 0.0f;
    #pragma unroll
    for (int i = 0; i < 7; ++i) {
        #pragma unroll
        for (int j = 0; j < 7; ++j) {
            acc += w[0][i * 7 + j] * t0[oy + i][ox + j];
            acc += w[1][i * 7 + j] * t1[oy + i][ox + j];
        }
    }

    float y = 1.0f / (1.0f + expf(-acc));
    out[b * HW + (ty0 + oy) * WW + (tx0 + ox)] = y;
}

// ---------------------------------------------------------------------------
extern "C" void kernel_launch(void* const* d_in, const int* in_sizes, int n_in,
                              void* d_out, int out_size, void* d_ws, size_t ws_size,
                              hipStream_t stream)
{
    const float* x  = (const float*)d_in[0];
    const float* wt = (const float*)d_in[1];
    float* out = (float*)d_out;

    // workspace: avg plane then max plane, each BATCH*HW floats (1.6 MB each)
    float* avgp = (float*)d_ws;
    float* maxp = avgp + (size_t)BATCH * HW;

    // Kernel 1: 7 x 32 = 224 blocks of 448 threads (7 KiB contiguous / c-step)
    dim3 grid1(HW4 / CHUNK, BATCH);
    sa_pool_kernel<<<grid1, CHUNK, 0, stream>>>(
        (const f32x4*)x, (f32x4*)avgp, (f32x4*)maxp);

    // Kernel 2: 7x7 tiles, 32 batches
    dim3 grid2(WW / TILE, HH / TILE, BATCH);
    sa_conv_kernel<<<grid2, 256, 0, stream>>>(avgp, maxp, wt, out);
}